// Round 5
// baseline (586.015 us; speedup 1.0000x reference)
//
#include <hip/hip_runtime.h>

#define F_IN 128
#define H1   16
#define C2   8
#define BSHIFT 7
#define BNODES 128            // nodes per bucket
#define MAXBUCK 1024          // LDS array bound (runtime nbuck=782)
#define NBLK 256              // blocks for binning passes

// ---------- pass 1: per-(bucket,block) destination-bucket histogram ----------
__global__ void binA_kernel(const int* __restrict__ col, int E, int chunk,
                            int nbuck, int* __restrict__ bbc) {
    __shared__ int h[MAXBUCK];
    for (int b = threadIdx.x; b < nbuck; b += blockDim.x) h[b] = 0;
    __syncthreads();
    int base = blockIdx.x * chunk;
    int lim = min(base + chunk, E);
    for (int e = base + threadIdx.x; e < lim; e += blockDim.x) {
        atomicAdd(&h[col[e] >> BSHIFT], 1);
    }
    __syncthreads();
    for (int b = threadIdx.x; b < nbuck; b += blockDim.x)
        bbc[b * NBLK + blockIdx.x] = h[b];
}

// ---------- exclusive scan over M = nbuck*NBLK values (3 kernels) ----------
__global__ void scanA_kernel(const int* __restrict__ in, int M,
                             int* __restrict__ outp, int* __restrict__ bsum) {
    __shared__ int s[256];
    int i = blockIdx.x * 256 + threadIdx.x;
    int v = (i < M) ? in[i] : 0;
    s[threadIdx.x] = v;
    __syncthreads();
    int incl = v;
    for (int off = 1; off < 256; off <<= 1) {
        int t = (threadIdx.x >= off) ? s[threadIdx.x - off] : 0;
        __syncthreads();
        incl += t;
        s[threadIdx.x] = incl;
        __syncthreads();
    }
    if (i < M) outp[i] = incl - v;
    if (threadIdx.x == 255) bsum[blockIdx.x] = incl;
}

__global__ void scanB_kernel(int* __restrict__ bsum, int* __restrict__ boff, int NB) {
    __shared__ int s[1024];
    int v = (threadIdx.x < NB) ? bsum[threadIdx.x] : 0;
    s[threadIdx.x] = v;
    __syncthreads();
    int incl = v;
    for (int off = 1; off < 1024; off <<= 1) {
        int t = (threadIdx.x >= off) ? s[threadIdx.x - off] : 0;
        __syncthreads();
        incl += t;
        s[threadIdx.x] = incl;
        __syncthreads();
    }
    boff[threadIdx.x] = incl - v;
}

__global__ void scanC_kernel(int* __restrict__ ptr, const int* __restrict__ boff, int M) {
    int i = blockIdx.x * 256 + threadIdx.x;
    if (i < M) ptr[i] += boff[blockIdx.x];
}

// ---------- pass 2: scatter packed records into bucket-major staging ----------
// record = (r << BSHIFT) | (c & (BNODES-1))
__global__ void binScatter_kernel(const int* __restrict__ ei, int E, int chunk,
                                  int nbuck, const int* __restrict__ bbcScan,
                                  int* __restrict__ stage) {
    __shared__ int cur[MAXBUCK];
    for (int b = threadIdx.x; b < nbuck; b += blockDim.x)
        cur[b] = bbcScan[b * NBLK + blockIdx.x];
    __syncthreads();
    int base = blockIdx.x * chunk;
    int lim = min(base + chunk, E);
    for (int e = base + threadIdx.x; e < lim; e += blockDim.x) {
        int r = ei[e];
        int c = ei[E + e];
        int p = atomicAdd(&cur[c >> BSHIFT], 1);
        stage[p] = (r << BSHIFT) | (c & (BNODES - 1));
    }
}

// ---------- per-bucket degree count -> dinv (fused) ----------
__global__ void degdinv_kernel(const int* __restrict__ stage, const int* __restrict__ bbcScan,
                               int E, int nbuck, float* __restrict__ dinv, int N) {
    __shared__ int deg[BNODES];
    int b = blockIdx.x;
    if (threadIdx.x < BNODES) deg[threadIdx.x] = 0;
    __syncthreads();
    int s = bbcScan[b * NBLK];
    int e_end = (b == nbuck - 1) ? E : bbcScan[(b + 1) * NBLK];
    for (int i = s + threadIdx.x; i < e_end; i += blockDim.x)
        atomicAdd(&deg[stage[i] & (BNODES - 1)], 1);
    __syncthreads();
    int v = b * BNODES + threadIdx.x;
    if (threadIdx.x < BNODES && v < N)
        dinv[v] = rsqrtf((float)deg[threadIdx.x] + 1.0f);
}

// ---------- h1s = (x @ W1) * dinv[v] ----------
__global__ void gemm1_kernel(const float* __restrict__ x, const float* __restrict__ W1,
                             const float* __restrict__ dinv, float* __restrict__ h1s, int N) {
    __shared__ float sW[F_IN * H1];
    for (int i = threadIdx.x; i < F_IN * H1; i += blockDim.x) sW[i] = W1[i];
    __syncthreads();
    int v = blockIdx.x * blockDim.x + threadIdx.x;
    if (v >= N) return;
    float acc[H1];
#pragma unroll
    for (int j = 0; j < H1; ++j) acc[j] = 0.0f;
    const float4* xr = reinterpret_cast<const float4*>(x + (size_t)v * F_IN);
#pragma unroll 8
    for (int k4 = 0; k4 < F_IN / 4; ++k4) {
        float4 xv = xr[k4];
        const float* w = &sW[k4 * 4 * H1];
#pragma unroll
        for (int j = 0; j < H1; ++j) acc[j] += xv.x * w[j];
#pragma unroll
        for (int j = 0; j < H1; ++j) acc[j] += xv.y * w[H1 + j];
#pragma unroll
        for (int j = 0; j < H1; ++j) acc[j] += xv.z * w[2 * H1 + j];
#pragma unroll
        for (int j = 0; j < H1; ++j) acc[j] += xv.w * w[3 * H1 + j];
    }
    float di = dinv[v];
    float4* ho = reinterpret_cast<float4*>(h1s + (size_t)v * H1);
#pragma unroll
    for (int q = 0; q < H1 / 4; ++q) {
        ho[q] = make_float4(acc[q * 4 + 0] * di, acc[q * 4 + 1] * di,
                            acc[q * 4 + 2] * di, acc[q * 4 + 3] * di);
    }
}

// ---------- layer-1 aggregation in LDS + relu + GEMM2 fused ----------
// Edge phase: ONE THREAD PER EDGE. Each lane loads its edge's full h1s row
// (4 independent float4 = 64 distinct lines per wave instruction) then does
// 16 LDS atomics. This maximizes memory-level parallelism per instruction.
#define AGG1_PAD 17
#define AGG1_TB  512
__global__ __launch_bounds__(AGG1_TB) void agg1_kernel(
        const int* __restrict__ stage, const int* __restrict__ bbcScan,
        int E, int nbuck, const float* __restrict__ h1s,
        const float* __restrict__ dinv, const float* __restrict__ b1,
        const float* __restrict__ W2, float* __restrict__ h2s, int N) {
    __shared__ float agg[BNODES * AGG1_PAD];
    __shared__ float sW[H1 * C2];
    __shared__ float sb[H1];
    for (int i = threadIdx.x; i < BNODES * AGG1_PAD; i += AGG1_TB) agg[i] = 0.0f;
    for (int i = threadIdx.x; i < H1 * C2; i += AGG1_TB) sW[i] = W2[i];
    for (int i = threadIdx.x; i < H1; i += AGG1_TB) sb[i] = b1[i];
    __syncthreads();

    int b = blockIdx.x;
    int base = b * BNODES;
    int s = bbcScan[b * NBLK];
    int e_end = (b == nbuck - 1) ? E : bbcScan[(b + 1) * NBLK];

    for (int i = s + (int)threadIdx.x; i < e_end; i += AGG1_TB) {
        int rec = stage[i];
        int r = rec >> BSHIFT;
        int cl = rec & (BNODES - 1);
        const float4* hr = reinterpret_cast<const float4*>(h1s + (size_t)r * H1);
        float4 a0 = hr[0];
        float4 a1 = hr[1];
        float4 a2 = hr[2];
        float4 a3 = hr[3];
        float* dst = &agg[cl * AGG1_PAD];
        atomicAdd(dst + 0,  a0.x);
        atomicAdd(dst + 1,  a0.y);
        atomicAdd(dst + 2,  a0.z);
        atomicAdd(dst + 3,  a0.w);
        atomicAdd(dst + 4,  a1.x);
        atomicAdd(dst + 5,  a1.y);
        atomicAdd(dst + 6,  a1.z);
        atomicAdd(dst + 7,  a1.w);
        atomicAdd(dst + 8,  a2.x);
        atomicAdd(dst + 9,  a2.y);
        atomicAdd(dst + 10, a2.z);
        atomicAdd(dst + 11, a2.w);
        atomicAdd(dst + 12, a3.x);
        atomicAdd(dst + 13, a3.y);
        atomicAdd(dst + 14, a3.z);
        atomicAdd(dst + 15, a3.w);
    }
    __syncthreads();

    // finalize: relu(dinv*(agg + self) + b1), store back to LDS
    const int f  = threadIdx.x & 15;
    const int ns = AGG1_TB >> 4;
    for (int vi = threadIdx.x >> 4; vi < BNODES; vi += ns) {
        int v = base + vi;
        if (v < N) {
            float hv = dinv[v] * (agg[vi * AGG1_PAD + f] + h1s[(size_t)v * H1 + f]) + sb[f];
            agg[vi * AGG1_PAD + f] = fmaxf(hv, 0.0f);
        }
    }
    __syncthreads();

    // GEMM2: h2s[v] = (hrelu @ W2) * dinv[v]
    int j = threadIdx.x & 7;
    for (int vi = threadIdx.x >> 3; vi < BNODES; vi += (AGG1_TB >> 3)) {
        int v = base + vi;
        if (v < N) {
            float dot = 0.0f;
#pragma unroll
            for (int k = 0; k < H1; ++k) dot += agg[vi * AGG1_PAD + k] * sW[k * C2 + j];
            h2s[(size_t)v * C2 + j] = dot * dinv[v];
        }
    }
}

// ---------- layer-2 aggregation in LDS + bias + log_softmax fused ----------
#define AGG2_PAD 9
#define AGG2_TB  512
__global__ __launch_bounds__(AGG2_TB) void agg2_kernel(
        const int* __restrict__ stage, const int* __restrict__ bbcScan,
        int E, int nbuck, const float* __restrict__ h2s,
        const float* __restrict__ dinv, const float* __restrict__ b2,
        float* __restrict__ out, int N) {
    __shared__ float agg[BNODES * AGG2_PAD];
    __shared__ float sb[C2];
    for (int i = threadIdx.x; i < BNODES * AGG2_PAD; i += AGG2_TB) agg[i] = 0.0f;
    if (threadIdx.x < C2) sb[threadIdx.x] = b2[threadIdx.x];
    __syncthreads();

    int b = blockIdx.x;
    int base = b * BNODES;
    int s = bbcScan[b * NBLK];
    int e_end = (b == nbuck - 1) ? E : bbcScan[(b + 1) * NBLK];

    for (int i = s + (int)threadIdx.x; i < e_end; i += AGG2_TB) {
        int rec = stage[i];
        int r = rec >> BSHIFT;
        int cl = rec & (BNODES - 1);
        const float4* hr = reinterpret_cast<const float4*>(h2s + (size_t)r * C2);
        float4 a0 = hr[0];
        float4 a1 = hr[1];
        float* dst = &agg[cl * AGG2_PAD];
        atomicAdd(dst + 0, a0.x);
        atomicAdd(dst + 1, a0.y);
        atomicAdd(dst + 2, a0.z);
        atomicAdd(dst + 3, a0.w);
        atomicAdd(dst + 4, a1.x);
        atomicAdd(dst + 5, a1.y);
        atomicAdd(dst + 6, a1.z);
        atomicAdd(dst + 7, a1.w);
    }
    __syncthreads();

    const int f  = threadIdx.x & 7;
    const int ns = AGG2_TB >> 3;
    for (int vi = threadIdx.x >> 3; vi < BNODES; vi += ns) {
        int v = base + vi;
        if (v < N) {
            float z = dinv[v] * (agg[vi * AGG2_PAD + f] + h2s[(size_t)v * C2 + f]) + sb[f];
            float m = z;
#pragma unroll
            for (int mask = 1; mask < 8; mask <<= 1)
                m = fmaxf(m, __shfl_xor(m, mask, 8));
            float ex = __expf(z - m);
            float ssum = ex;
#pragma unroll
            for (int mask = 1; mask < 8; mask <<= 1)
                ssum += __shfl_xor(ssum, mask, 8);
            float lse = m + logf(ssum);
            out[(size_t)v * C2 + f] = z - lse;
        }
    }
}

extern "C" void kernel_launch(void* const* d_in, const int* in_sizes, int n_in,
                              void* d_out, int out_size, void* d_ws, size_t ws_size,
                              hipStream_t stream) {
    const float* x  = (const float*)d_in[0];
    const int*   ei = (const int*)d_in[1];
    const float* W1 = (const float*)d_in[2];
    const float* b1 = (const float*)d_in[3];
    const float* W2 = (const float*)d_in[4];
    const float* b2 = (const float*)d_in[5];
    float* out = (float*)d_out;

    const int N = in_sizes[0] / F_IN;
    const int E = in_sizes[1] / 2;
    const int nbuck = (N + BNODES - 1) >> BSHIFT;        // 782
    const int M = nbuck * NBLK;                          // 200192
    const int chunk = (E + NBLK - 1) / NBLK;             // 12500

    // workspace layout (ints/floats, 4B each)
    int*   stage   = (int*)d_ws;                         // E
    int*   bbc     = stage + E;                          // M
    int*   bbcScan = bbc + M;                            // M
    int*   bsum    = bbcScan + M;                        // 1024
    int*   boff    = bsum + 1024;                        // 1024
    float* dinv    = (float*)(boff + 1024);              // N
    float* h1s     = dinv + N;                           // 16N
    float* h2s     = h1s + (size_t)16 * N;               // 8N

    const int TB = 256;
    const int scanBlocks = (M + 255) / 256;              // = nbuck

    binA_kernel<<<NBLK, TB, 0, stream>>>(ei + E, E, chunk, nbuck, bbc);
    scanA_kernel<<<scanBlocks, TB, 0, stream>>>(bbc, M, bbcScan, bsum);
    scanB_kernel<<<1, 1024, 0, stream>>>(bsum, boff, scanBlocks);
    scanC_kernel<<<scanBlocks, TB, 0, stream>>>(bbcScan, boff, M);
    binScatter_kernel<<<NBLK, TB, 0, stream>>>(ei, E, chunk, nbuck, bbcScan, stage);
    degdinv_kernel<<<nbuck, TB, 0, stream>>>(stage, bbcScan, E, nbuck, dinv, N);
    gemm1_kernel<<<(N + TB - 1) / TB, TB, 0, stream>>>(x, W1, dinv, h1s, N);
    agg1_kernel<<<nbuck, AGG1_TB, 0, stream>>>(stage, bbcScan, E, nbuck, h1s, dinv, b1, W2, h2s, N);
    agg2_kernel<<<nbuck, AGG2_TB, 0, stream>>>(stage, bbcScan, E, nbuck, h2s, dinv, b2, out, N);
}

// Round 6
// 584.803 us; speedup vs baseline: 1.0021x; 1.0021x over previous
//
#include <hip/hip_runtime.h>
#include <hip/hip_fp16.h>

#define F_IN 128
#define H1   16
#define C2   8
#define BSHIFT 7
#define BNODES 128            // nodes per bucket
#define MAXBUCK 1024          // LDS array bound (runtime nbuck=782)
#define NBLK 256              // blocks for binning passes

// ---------- pass 1: per-(bucket,block) destination-bucket histogram ----------
__global__ void binA_kernel(const int* __restrict__ col, int E, int chunk,
                            int nbuck, int* __restrict__ bbc) {
    __shared__ int h[MAXBUCK];
    for (int b = threadIdx.x; b < nbuck; b += blockDim.x) h[b] = 0;
    __syncthreads();
    int base = blockIdx.x * chunk;
    int lim = min(base + chunk, E);
    for (int e = base + threadIdx.x; e < lim; e += blockDim.x) {
        atomicAdd(&h[col[e] >> BSHIFT], 1);
    }
    __syncthreads();
    for (int b = threadIdx.x; b < nbuck; b += blockDim.x)
        bbc[b * NBLK + blockIdx.x] = h[b];
}

// ---------- exclusive scan over M = nbuck*NBLK values (3 kernels) ----------
__global__ void scanA_kernel(const int* __restrict__ in, int M,
                             int* __restrict__ outp, int* __restrict__ bsum) {
    __shared__ int s[256];
    int i = blockIdx.x * 256 + threadIdx.x;
    int v = (i < M) ? in[i] : 0;
    s[threadIdx.x] = v;
    __syncthreads();
    int incl = v;
    for (int off = 1; off < 256; off <<= 1) {
        int t = (threadIdx.x >= off) ? s[threadIdx.x - off] : 0;
        __syncthreads();
        incl += t;
        s[threadIdx.x] = incl;
        __syncthreads();
    }
    if (i < M) outp[i] = incl - v;
    if (threadIdx.x == 255) bsum[blockIdx.x] = incl;
}

__global__ void scanB_kernel(int* __restrict__ bsum, int* __restrict__ boff, int NB) {
    __shared__ int s[1024];
    int v = (threadIdx.x < NB) ? bsum[threadIdx.x] : 0;
    s[threadIdx.x] = v;
    __syncthreads();
    int incl = v;
    for (int off = 1; off < 1024; off <<= 1) {
        int t = (threadIdx.x >= off) ? s[threadIdx.x - off] : 0;
        __syncthreads();
        incl += t;
        s[threadIdx.x] = incl;
        __syncthreads();
    }
    boff[threadIdx.x] = incl - v;
}

__global__ void scanC_kernel(int* __restrict__ ptr, const int* __restrict__ boff, int M) {
    int i = blockIdx.x * 256 + threadIdx.x;
    if (i < M) ptr[i] += boff[blockIdx.x];
}

// ---------- pass 2: scatter packed records into bucket-major staging ----------
// record = (r << BSHIFT) | (c & (BNODES-1))
__global__ void binScatter_kernel(const int* __restrict__ ei, int E, int chunk,
                                  int nbuck, const int* __restrict__ bbcScan,
                                  int* __restrict__ stage) {
    __shared__ int cur[MAXBUCK];
    for (int b = threadIdx.x; b < nbuck; b += blockDim.x)
        cur[b] = bbcScan[b * NBLK + blockIdx.x];
    __syncthreads();
    int base = blockIdx.x * chunk;
    int lim = min(base + chunk, E);
    for (int e = base + threadIdx.x; e < lim; e += blockDim.x) {
        int r = ei[e];
        int c = ei[E + e];
        int p = atomicAdd(&cur[c >> BSHIFT], 1);
        stage[p] = (r << BSHIFT) | (c & (BNODES - 1));
    }
}

// ---------- per-bucket degree count -> dinv (fused) ----------
__global__ void degdinv_kernel(const int* __restrict__ stage, const int* __restrict__ bbcScan,
                               int E, int nbuck, float* __restrict__ dinv, int N) {
    __shared__ int deg[BNODES];
    int b = blockIdx.x;
    if (threadIdx.x < BNODES) deg[threadIdx.x] = 0;
    __syncthreads();
    int s = bbcScan[b * NBLK];
    int e_end = (b == nbuck - 1) ? E : bbcScan[(b + 1) * NBLK];
    for (int i = s + threadIdx.x; i < e_end; i += blockDim.x)
        atomicAdd(&deg[stage[i] & (BNODES - 1)], 1);
    __syncthreads();
    int v = b * BNODES + threadIdx.x;
    if (threadIdx.x < BNODES && v < N)
        dinv[v] = rsqrtf((float)deg[threadIdx.x] + 1.0f);
}

// ---------- h1h = fp16( (x @ W1) * dinv[v] )  -- 3.2 MB table, fits per-XCD L2 ----------
__global__ void gemm1_kernel(const float* __restrict__ x, const float* __restrict__ W1,
                             const float* __restrict__ dinv, __half* __restrict__ h1h, int N) {
    __shared__ float sW[F_IN * H1];
    for (int i = threadIdx.x; i < F_IN * H1; i += blockDim.x) sW[i] = W1[i];
    __syncthreads();
    int v = blockIdx.x * blockDim.x + threadIdx.x;
    if (v >= N) return;
    float acc[H1];
#pragma unroll
    for (int j = 0; j < H1; ++j) acc[j] = 0.0f;
    const float4* xr = reinterpret_cast<const float4*>(x + (size_t)v * F_IN);
#pragma unroll 8
    for (int k4 = 0; k4 < F_IN / 4; ++k4) {
        float4 xv = xr[k4];
        const float* w = &sW[k4 * 4 * H1];
#pragma unroll
        for (int j = 0; j < H1; ++j) acc[j] += xv.x * w[j];
#pragma unroll
        for (int j = 0; j < H1; ++j) acc[j] += xv.y * w[H1 + j];
#pragma unroll
        for (int j = 0; j < H1; ++j) acc[j] += xv.z * w[2 * H1 + j];
#pragma unroll
        for (int j = 0; j < H1; ++j) acc[j] += xv.w * w[3 * H1 + j];
    }
    float di = dinv[v];
    alignas(16) __half2 hp[8];
#pragma unroll
    for (int q = 0; q < 8; ++q)
        hp[q] = __floats2half2_rn(acc[2 * q] * di, acc[2 * q + 1] * di);
    float4* ho = reinterpret_cast<float4*>(h1h + (size_t)v * H1);
    ho[0] = *reinterpret_cast<float4*>(&hp[0]);
    ho[1] = *reinterpret_cast<float4*>(&hp[4]);
}

// ---------- layer-1 aggregation in LDS + relu + GEMM2 fused ----------
// One thread per edge; gather = 32 B fp16 row (2 x float4 loads) from the
// L2-resident 3.2 MB h1h table; 16 LDS atomics into the padded bucket tile.
#define AGG1_PAD 17
#define AGG1_TB  512
__global__ __launch_bounds__(AGG1_TB) void agg1_kernel(
        const int* __restrict__ stage, const int* __restrict__ bbcScan,
        int E, int nbuck, const __half* __restrict__ h1h,
        const float* __restrict__ dinv, const float* __restrict__ b1,
        const float* __restrict__ W2, float* __restrict__ h2s, int N) {
    __shared__ float agg[BNODES * AGG1_PAD];
    __shared__ float sW[H1 * C2];
    __shared__ float sb[H1];
    for (int i = threadIdx.x; i < BNODES * AGG1_PAD; i += AGG1_TB) agg[i] = 0.0f;
    for (int i = threadIdx.x; i < H1 * C2; i += AGG1_TB) sW[i] = W2[i];
    for (int i = threadIdx.x; i < H1; i += AGG1_TB) sb[i] = b1[i];
    __syncthreads();

    int b = blockIdx.x;
    int base = b * BNODES;
    int s = bbcScan[b * NBLK];
    int e_end = (b == nbuck - 1) ? E : bbcScan[(b + 1) * NBLK];

    for (int i = s + (int)threadIdx.x; i < e_end; i += AGG1_TB) {
        int rec = stage[i];
        int r = rec >> BSHIFT;
        int cl = rec & (BNODES - 1);
        const float4* hr = reinterpret_cast<const float4*>(h1h + (size_t)r * H1);
        float4 p0 = hr[0];
        float4 p1 = hr[1];
        const __half2* q0 = reinterpret_cast<const __half2*>(&p0);
        const __half2* q1 = reinterpret_cast<const __half2*>(&p1);
        float* dst = &agg[cl * AGG1_PAD];
#pragma unroll
        for (int k = 0; k < 4; ++k) {
            float2 fv = __half22float2(q0[k]);
            atomicAdd(dst + 2 * k, fv.x);
            atomicAdd(dst + 2 * k + 1, fv.y);
        }
#pragma unroll
        for (int k = 0; k < 4; ++k) {
            float2 fv = __half22float2(q1[k]);
            atomicAdd(dst + 8 + 2 * k, fv.x);
            atomicAdd(dst + 8 + 2 * k + 1, fv.y);
        }
    }
    __syncthreads();

    // finalize: relu(dinv*(agg + self) + b1), store back to LDS
    const int f  = threadIdx.x & 15;
    const int ns = AGG1_TB >> 4;
    for (int vi = threadIdx.x >> 4; vi < BNODES; vi += ns) {
        int v = base + vi;
        if (v < N) {
            float self = __half2float(h1h[(size_t)v * H1 + f]);
            float hv = dinv[v] * (agg[vi * AGG1_PAD + f] + self) + sb[f];
            agg[vi * AGG1_PAD + f] = fmaxf(hv, 0.0f);
        }
    }
    __syncthreads();

    // GEMM2: h2s[v] = (hrelu @ W2) * dinv[v]
    int j = threadIdx.x & 7;
    for (int vi = threadIdx.x >> 3; vi < BNODES; vi += (AGG1_TB >> 3)) {
        int v = base + vi;
        if (v < N) {
            float dot = 0.0f;
#pragma unroll
            for (int k = 0; k < H1; ++k) dot += agg[vi * AGG1_PAD + k] * sW[k * C2 + j];
            h2s[(size_t)v * C2 + j] = dot * dinv[v];
        }
    }
}

// ---------- layer-2 aggregation in LDS + bias + log_softmax fused ----------
#define AGG2_PAD 9
#define AGG2_TB  512
__global__ __launch_bounds__(AGG2_TB) void agg2_kernel(
        const int* __restrict__ stage, const int* __restrict__ bbcScan,
        int E, int nbuck, const float* __restrict__ h2s,
        const float* __restrict__ dinv, const float* __restrict__ b2,
        float* __restrict__ out, int N) {
    __shared__ float agg[BNODES * AGG2_PAD];
    __shared__ float sb[C2];
    for (int i = threadIdx.x; i < BNODES * AGG2_PAD; i += AGG2_TB) agg[i] = 0.0f;
    if (threadIdx.x < C2) sb[threadIdx.x] = b2[threadIdx.x];
    __syncthreads();

    int b = blockIdx.x;
    int base = b * BNODES;
    int s = bbcScan[b * NBLK];
    int e_end = (b == nbuck - 1) ? E : bbcScan[(b + 1) * NBLK];

    for (int i = s + (int)threadIdx.x; i < e_end; i += AGG2_TB) {
        int rec = stage[i];
        int r = rec >> BSHIFT;
        int cl = rec & (BNODES - 1);
        const float4* hr = reinterpret_cast<const float4*>(h2s + (size_t)r * C2);
        float4 a0 = hr[0];
        float4 a1 = hr[1];
        float* dst = &agg[cl * AGG2_PAD];
        atomicAdd(dst + 0, a0.x);
        atomicAdd(dst + 1, a0.y);
        atomicAdd(dst + 2, a0.z);
        atomicAdd(dst + 3, a0.w);
        atomicAdd(dst + 4, a1.x);
        atomicAdd(dst + 5, a1.y);
        atomicAdd(dst + 6, a1.z);
        atomicAdd(dst + 7, a1.w);
    }
    __syncthreads();

    const int f  = threadIdx.x & 7;
    const int ns = AGG2_TB >> 3;
    for (int vi = threadIdx.x >> 3; vi < BNODES; vi += ns) {
        int v = base + vi;
        if (v < N) {
            float z = dinv[v] * (agg[vi * AGG2_PAD + f] + h2s[(size_t)v * C2 + f]) + sb[f];
            float m = z;
#pragma unroll
            for (int mask = 1; mask < 8; mask <<= 1)
                m = fmaxf(m, __shfl_xor(m, mask, 8));
            float ex = __expf(z - m);
            float ssum = ex;
#pragma unroll
            for (int mask = 1; mask < 8; mask <<= 1)
                ssum += __shfl_xor(ssum, mask, 8);
            float lse = m + logf(ssum);
            out[(size_t)v * C2 + f] = z - lse;
        }
    }
}

extern "C" void kernel_launch(void* const* d_in, const int* in_sizes, int n_in,
                              void* d_out, int out_size, void* d_ws, size_t ws_size,
                              hipStream_t stream) {
    const float* x  = (const float*)d_in[0];
    const int*   ei = (const int*)d_in[1];
    const float* W1 = (const float*)d_in[2];
    const float* b1 = (const float*)d_in[3];
    const float* W2 = (const float*)d_in[4];
    const float* b2 = (const float*)d_in[5];
    float* out = (float*)d_out;

    const int N = in_sizes[0] / F_IN;
    const int E = in_sizes[1] / 2;
    const int nbuck = (N + BNODES - 1) >> BSHIFT;        // 782
    const int M = nbuck * NBLK;                          // 200192
    const int chunk = (E + NBLK - 1) / NBLK;             // 12500

    // workspace layout (4B units)
    int*    stage   = (int*)d_ws;                        // E
    int*    bbc     = stage + E;                         // M
    int*    bbcScan = bbc + M;                           // M
    int*    bsum    = bbcScan + M;                       // 1024
    int*    boff    = bsum + 1024;                       // 1024
    float*  dinv    = (float*)(boff + 1024);             // N
    __half* h1h     = (__half*)(dinv + N);               // 16N halves (8N floats worth)
    float*  h2s     = (float*)(h1h + (size_t)16 * N);    // 8N
    // (h1h offset is 16B-aligned: (E + 2M + 2048 + N) * 4 is divisible by 16)

    const int TB = 256;
    const int scanBlocks = (M + 255) / 256;              // = nbuck

    binA_kernel<<<NBLK, TB, 0, stream>>>(ei + E, E, chunk, nbuck, bbc);
    scanA_kernel<<<scanBlocks, TB, 0, stream>>>(bbc, M, bbcScan, bsum);
    scanB_kernel<<<1, 1024, 0, stream>>>(bsum, boff, scanBlocks);
    scanC_kernel<<<scanBlocks, TB, 0, stream>>>(bbcScan, boff, M);
    binScatter_kernel<<<NBLK, TB, 0, stream>>>(ei, E, chunk, nbuck, bbcScan, stage);
    degdinv_kernel<<<nbuck, TB, 0, stream>>>(stage, bbcScan, E, nbuck, dinv, N);
    gemm1_kernel<<<(N + TB - 1) / TB, TB, 0, stream>>>(x, W1, dinv, h1h, N);
    agg1_kernel<<<nbuck, AGG1_TB, 0, stream>>>(stage, bbcScan, E, nbuck, h1h, dinv, b1, W2, h2s, N);
    agg2_kernel<<<nbuck, AGG2_TB, 0, stream>>>(stage, bbcScan, E, nbuck, h2s, dinv, b2, out, N);
}

// Round 7
// 155.768 us; speedup vs baseline: 3.7621x; 3.7543x over previous
//
#include <hip/hip_runtime.h>
#include <hip/hip_fp16.h>

#define F_IN 128
#define H1   16
#define C2   8
#define BSHIFT 7
#define BNODES 128            // nodes per bucket
#define MAXBUCK 1024          // LDS array bound (runtime nbuck=782)
#define NBLK 256              // blocks for binning passes

// ---------- pass 1: per-(bucket,block) destination-bucket histogram ----------
__global__ void binA_kernel(const int* __restrict__ col, int E, int chunk,
                            int nbuck, int* __restrict__ bbc) {
    __shared__ int h[MAXBUCK];
    for (int b = threadIdx.x; b < nbuck; b += blockDim.x) h[b] = 0;
    __syncthreads();
    int base = blockIdx.x * chunk;
    int lim = min(base + chunk, E);
    for (int e = base + threadIdx.x; e < lim; e += blockDim.x) {
        atomicAdd(&h[col[e] >> BSHIFT], 1);
    }
    __syncthreads();
    for (int b = threadIdx.x; b < nbuck; b += blockDim.x)
        bbc[b * NBLK + blockIdx.x] = h[b];
}

// ---------- exclusive scan over M = nbuck*NBLK values (3 kernels) ----------
__global__ void scanA_kernel(const int* __restrict__ in, int M,
                             int* __restrict__ outp, int* __restrict__ bsum) {
    __shared__ int s[256];
    int i = blockIdx.x * 256 + threadIdx.x;
    int v = (i < M) ? in[i] : 0;
    s[threadIdx.x] = v;
    __syncthreads();
    int incl = v;
    for (int off = 1; off < 256; off <<= 1) {
        int t = (threadIdx.x >= off) ? s[threadIdx.x - off] : 0;
        __syncthreads();
        incl += t;
        s[threadIdx.x] = incl;
        __syncthreads();
    }
    if (i < M) outp[i] = incl - v;
    if (threadIdx.x == 255) bsum[blockIdx.x] = incl;
}

__global__ void scanB_kernel(int* __restrict__ bsum, int* __restrict__ boff, int NB) {
    __shared__ int s[1024];
    int v = (threadIdx.x < NB) ? bsum[threadIdx.x] : 0;
    s[threadIdx.x] = v;
    __syncthreads();
    int incl = v;
    for (int off = 1; off < 1024; off <<= 1) {
        int t = (threadIdx.x >= off) ? s[threadIdx.x - off] : 0;
        __syncthreads();
        incl += t;
        s[threadIdx.x] = incl;
        __syncthreads();
    }
    boff[threadIdx.x] = incl - v;
}

__global__ void scanC_kernel(int* __restrict__ ptr, const int* __restrict__ boff, int M) {
    int i = blockIdx.x * 256 + threadIdx.x;
    if (i < M) ptr[i] += boff[blockIdx.x];
}

// ---------- pass 2: scatter packed records into bucket-major staging ----------
// record = (r << BSHIFT) | (c & (BNODES-1))
__global__ void binScatter_kernel(const int* __restrict__ ei, int E, int chunk,
                                  int nbuck, const int* __restrict__ bbcScan,
                                  int* __restrict__ stage) {
    __shared__ int cur[MAXBUCK];
    for (int b = threadIdx.x; b < nbuck; b += blockDim.x)
        cur[b] = bbcScan[b * NBLK + blockIdx.x];
    __syncthreads();
    int base = blockIdx.x * chunk;
    int lim = min(base + chunk, E);
    for (int e = base + threadIdx.x; e < lim; e += blockDim.x) {
        int r = ei[e];
        int c = ei[E + e];
        int p = atomicAdd(&cur[c >> BSHIFT], 1);
        stage[p] = (r << BSHIFT) | (c & (BNODES - 1));
    }
}

// ---------- pass 3: within-bucket counting sort by destination node ----------
// Produces srt[] (source node per edge, grouped by dest), nodePtr[N+1], dinv[N].
__global__ void sortCSR_kernel(const int* __restrict__ stage, const int* __restrict__ bbcScan,
                               int E, int nbuck, int* __restrict__ srt,
                               int* __restrict__ nodePtr, float* __restrict__ dinv, int N) {
    __shared__ int cnt[BNODES];
    __shared__ int cur[BNODES];
    int b = blockIdx.x;
    int s = bbcScan[b * NBLK];
    int e_end = (b == nbuck - 1) ? E : bbcScan[(b + 1) * NBLK];

    if (threadIdx.x < BNODES) cnt[threadIdx.x] = 0;
    __syncthreads();
    for (int i = s + (int)threadIdx.x; i < e_end; i += blockDim.x)
        atomicAdd(&cnt[stage[i] & (BNODES - 1)], 1);
    __syncthreads();

    // exclusive scan of cnt[128] (Hillis-Steele in cur)
    if (threadIdx.x < BNODES) cur[threadIdx.x] = cnt[threadIdx.x];
    __syncthreads();
    for (int off = 1; off < BNODES; off <<= 1) {
        int t = 0;
        if (threadIdx.x < BNODES && threadIdx.x >= off) t = cur[threadIdx.x - off];
        __syncthreads();
        if (threadIdx.x < BNODES) cur[threadIdx.x] += t;
        __syncthreads();
    }
    if (threadIdx.x < BNODES) {
        int excl = cur[threadIdx.x] - cnt[threadIdx.x];
        int v = b * BNODES + threadIdx.x;
        if (v < N) {
            nodePtr[v] = s + excl;
            dinv[v] = rsqrtf((float)cnt[threadIdx.x] + 1.0f);
        }
        cur[threadIdx.x] = excl;
    }
    if (b == nbuck - 1 && threadIdx.x == 0) nodePtr[N] = E;
    __syncthreads();

    for (int i = s + (int)threadIdx.x; i < e_end; i += blockDim.x) {
        int rec = stage[i];
        int p = s + atomicAdd(&cur[rec & (BNODES - 1)], 1);
        srt[p] = rec >> BSHIFT;
    }
}

// ---------- h1h = fp16( (x @ W1) * dinv[v] )  -- 3.2 MB, L2-resident ----------
__global__ void gemm1_kernel(const float* __restrict__ x, const float* __restrict__ W1,
                             const float* __restrict__ dinv, __half* __restrict__ h1h, int N) {
    __shared__ float sW[F_IN * H1];
    for (int i = threadIdx.x; i < F_IN * H1; i += blockDim.x) sW[i] = W1[i];
    __syncthreads();
    int v = blockIdx.x * blockDim.x + threadIdx.x;
    if (v >= N) return;
    float acc[H1];
#pragma unroll
    for (int j = 0; j < H1; ++j) acc[j] = 0.0f;
    const float4* xr = reinterpret_cast<const float4*>(x + (size_t)v * F_IN);
#pragma unroll 8
    for (int k4 = 0; k4 < F_IN / 4; ++k4) {
        float4 xv = xr[k4];
        const float* w = &sW[k4 * 4 * H1];
#pragma unroll
        for (int j = 0; j < H1; ++j) acc[j] += xv.x * w[j];
#pragma unroll
        for (int j = 0; j < H1; ++j) acc[j] += xv.y * w[H1 + j];
#pragma unroll
        for (int j = 0; j < H1; ++j) acc[j] += xv.z * w[2 * H1 + j];
#pragma unroll
        for (int j = 0; j < H1; ++j) acc[j] += xv.w * w[3 * H1 + j];
    }
    float di = dinv[v];
    alignas(16) __half2 hp[8];
#pragma unroll
    for (int q = 0; q < 8; ++q)
        hp[q] = __floats2half2_rn(acc[2 * q] * di, acc[2 * q + 1] * di);
    float4* ho = reinterpret_cast<float4*>(h1h + (size_t)v * H1);
    ho[0] = *reinterpret_cast<float4*>(&hp[0]);
    ho[1] = *reinterpret_cast<float4*>(&hp[4]);
}

// ---------- layer-1: atomic-free gather over CSR + relu + GEMM2 fused ----------
// 8-lane group per node (each lane = 2 features via half2), registers accumulate,
// 4-way unrolled independent loads for MLP.
#define AGG1_TB 512
__global__ __launch_bounds__(AGG1_TB) void agg1_kernel(
        const int* __restrict__ srt, const int* __restrict__ nodePtr,
        const __half* __restrict__ h1h, const float* __restrict__ dinv,
        const float* __restrict__ b1, const float* __restrict__ W2,
        float* __restrict__ h2s, int N) {
    __shared__ float hrelu[BNODES][H1 + 1];
    __shared__ float sW[H1 * C2];
    __shared__ float sb[H1];
    for (int i = threadIdx.x; i < H1 * C2; i += AGG1_TB) sW[i] = W2[i];
    for (int i = threadIdx.x; i < H1; i += AGG1_TB) sb[i] = b1[i];
    __syncthreads();

    int base = blockIdx.x * BNODES;
    int g  = threadIdx.x >> 3;     // 64 groups of 8 lanes
    int f2 = threadIdx.x & 7;      // half2 slot: features 2*f2, 2*f2+1
    const __half2* hp = reinterpret_cast<const __half2*>(h1h);

    for (int vi = g; vi < BNODES; vi += (AGG1_TB >> 3)) {
        int v = base + vi;
        if (v >= N) break;
        int p  = nodePtr[v];
        int pe = nodePtr[v + 1];
        float ax0 = 0.f, ay0 = 0.f, ax1 = 0.f, ay1 = 0.f;
        float ax2 = 0.f, ay2 = 0.f, ax3 = 0.f, ay3 = 0.f;
        int e = p;
        for (; e + 3 < pe; e += 4) {
            int r0 = srt[e];
            int r1 = srt[e + 1];
            int r2 = srt[e + 2];
            int r3 = srt[e + 3];
            float2 t0 = __half22float2(hp[r0 * (H1 / 2) + f2]);
            float2 t1 = __half22float2(hp[r1 * (H1 / 2) + f2]);
            float2 t2 = __half22float2(hp[r2 * (H1 / 2) + f2]);
            float2 t3 = __half22float2(hp[r3 * (H1 / 2) + f2]);
            ax0 += t0.x; ay0 += t0.y;
            ax1 += t1.x; ay1 += t1.y;
            ax2 += t2.x; ay2 += t2.y;
            ax3 += t3.x; ay3 += t3.y;
        }
        for (; e < pe; ++e) {
            float2 t = __half22float2(hp[srt[e] * (H1 / 2) + f2]);
            ax0 += t.x; ay0 += t.y;
        }
        float2 self = __half22float2(hp[(size_t)v * (H1 / 2) + f2]);
        float sx = ax0 + ax1 + ax2 + ax3 + self.x;
        float sy = ay0 + ay1 + ay2 + ay3 + self.y;
        float di = dinv[v];
        hrelu[vi][2 * f2]     = fmaxf(di * sx + sb[2 * f2], 0.0f);
        hrelu[vi][2 * f2 + 1] = fmaxf(di * sy + sb[2 * f2 + 1], 0.0f);
    }
    __syncthreads();

    // GEMM2: h2s[v] = (hrelu @ W2) * dinv[v]
    int j = threadIdx.x & 7;
    for (int vi = threadIdx.x >> 3; vi < BNODES; vi += (AGG1_TB >> 3)) {
        int v = base + vi;
        if (v < N) {
            float dot = 0.0f;
#pragma unroll
            for (int k = 0; k < H1; ++k) dot += hrelu[vi][k] * sW[k * C2 + j];
            h2s[(size_t)v * C2 + j] = dot * dinv[v];
        }
    }
}

// ---------- layer-2: atomic-free gather + bias + log_softmax fused ----------
#define AGG2_TB 512
__global__ __launch_bounds__(AGG2_TB) void agg2_kernel(
        const int* __restrict__ srt, const int* __restrict__ nodePtr,
        const float* __restrict__ h2s, const float* __restrict__ dinv,
        const float* __restrict__ b2, float* __restrict__ out, int N) {
    __shared__ float sb[C2];
    if (threadIdx.x < C2) sb[threadIdx.x] = b2[threadIdx.x];
    __syncthreads();

    int base = blockIdx.x * BNODES;
    int g = threadIdx.x >> 3;      // 64 groups of 8 lanes
    int f = threadIdx.x & 7;       // class lane

    for (int vi = g; vi < BNODES; vi += (AGG2_TB >> 3)) {
        int v = base + vi;
        if (v >= N) break;
        int p  = nodePtr[v];
        int pe = nodePtr[v + 1];
        float a0 = 0.f, a1 = 0.f, a2 = 0.f, a3 = 0.f;
        int e = p;
        for (; e + 3 < pe; e += 4) {
            int r0 = srt[e];
            int r1 = srt[e + 1];
            int r2 = srt[e + 2];
            int r3 = srt[e + 3];
            a0 += h2s[(size_t)r0 * C2 + f];
            a1 += h2s[(size_t)r1 * C2 + f];
            a2 += h2s[(size_t)r2 * C2 + f];
            a3 += h2s[(size_t)r3 * C2 + f];
        }
        for (; e < pe; ++e) a0 += h2s[(size_t)srt[e] * C2 + f];
        float z = dinv[v] * (a0 + a1 + a2 + a3 + h2s[(size_t)v * C2 + f]) + sb[f];

        float m = z;
#pragma unroll
        for (int mask = 1; mask < 8; mask <<= 1)
            m = fmaxf(m, __shfl_xor(m, mask, 8));
        float ex = __expf(z - m);
        float ssum = ex;
#pragma unroll
        for (int mask = 1; mask < 8; mask <<= 1)
            ssum += __shfl_xor(ssum, mask, 8);
        float lse = m + logf(ssum);
        out[(size_t)v * C2 + f] = z - lse;
    }
}

extern "C" void kernel_launch(void* const* d_in, const int* in_sizes, int n_in,
                              void* d_out, int out_size, void* d_ws, size_t ws_size,
                              hipStream_t stream) {
    const float* x  = (const float*)d_in[0];
    const int*   ei = (const int*)d_in[1];
    const float* W1 = (const float*)d_in[2];
    const float* b1 = (const float*)d_in[3];
    const float* W2 = (const float*)d_in[4];
    const float* b2 = (const float*)d_in[5];
    float* out = (float*)d_out;

    const int N = in_sizes[0] / F_IN;
    const int E = in_sizes[1] / 2;
    const int nbuck = (N + BNODES - 1) >> BSHIFT;        // 782
    const int M = nbuck * NBLK;                          // 200192
    const int chunk = (E + NBLK - 1) / NBLK;             // 12500

    // workspace layout (4B units); nodePtr padded to N+8 to keep h1h 16B-aligned
    int*    stage   = (int*)d_ws;                        // E
    int*    srt     = stage + E;                         // E
    int*    bbc     = srt + E;                           // M
    int*    bbcScan = bbc + M;                           // M
    int*    bsum    = bbcScan + M;                       // 1024
    int*    boff    = bsum + 1024;                       // 1024
    int*    nodePtr = boff + 1024;                       // N+8 (N+1 used)
    float*  dinv    = (float*)(nodePtr + N + 8);         // N
    __half* h1h     = (__half*)(dinv + N);               // 16N halves
    float*  h2s     = (float*)(h1h + (size_t)16 * N);    // 8N

    const int TB = 256;
    const int scanBlocks = (M + 255) / 256;              // = nbuck

    binA_kernel<<<NBLK, TB, 0, stream>>>(ei + E, E, chunk, nbuck, bbc);
    scanA_kernel<<<scanBlocks, TB, 0, stream>>>(bbc, M, bbcScan, bsum);
    scanB_kernel<<<1, 1024, 0, stream>>>(bsum, boff, scanBlocks);
    scanC_kernel<<<scanBlocks, TB, 0, stream>>>(bbcScan, boff, M);
    binScatter_kernel<<<NBLK, TB, 0, stream>>>(ei, E, chunk, nbuck, bbcScan, stage);
    sortCSR_kernel<<<nbuck, TB, 0, stream>>>(stage, bbcScan, E, nbuck, srt, nodePtr, dinv, N);
    gemm1_kernel<<<(N + TB - 1) / TB, TB, 0, stream>>>(x, W1, dinv, h1h, N);
    agg1_kernel<<<nbuck, AGG1_TB, 0, stream>>>(srt, nodePtr, h1h, dinv, b1, W2, h2s, N);
    agg2_kernel<<<nbuck, AGG2_TB, 0, stream>>>(srt, nodePtr, h2s, dinv, b2, out, N);
}